// Round 6
// baseline (229.507 us; speedup 1.0000x reference)
//
#include <hip/hip_runtime.h>

// Problem constants: L=1024, B=16, X=512, Y=512, Q=64, NUM_D=4, H_LOW=128
typedef __bf16 bf16x8 __attribute__((ext_vector_type(8)));
typedef float f32x4 __attribute__((ext_vector_type(4)));

__device__ __forceinline__ unsigned short f2bf_bits(float f) {
    unsigned int u = __builtin_bit_cast(unsigned int, f);
    u += 0x7fffu + ((u >> 16) & 1u);
    return (unsigned short)(u >> 16);
}
__device__ __forceinline__ float bf2f(unsigned short b) {
    return __builtin_bit_cast(float, (unsigned int)b << 16);
}
__device__ __forceinline__ unsigned int pk2(float a, float b) {
    unsigned int r;
    asm("v_cvt_pk_bf16_f32 %0, %1, %2" : "=v"(r) : "v"(a), "v"(b));
    return r;
}
__device__ __forceinline__ bf16x8 ld8(const unsigned short* p) {
    return __builtin_bit_cast(bf16x8, *reinterpret_cast<const uint4*>(p));
}
__device__ __forceinline__ f32x4 mfma16(bf16x8 a, bf16x8 b, f32x4 c) {
    return __builtin_amdgcn_mfma_f32_16x16x32_bf16(a, b, c, 0, 0, 0);
}
__device__ __forceinline__ void gload16(const unsigned short* g, unsigned short* lds) {
    __builtin_amdgcn_global_load_lds(
        (const __attribute__((address_space(1))) unsigned int*)g,
        (__attribute__((address_space(3))) unsigned int*)lds, 16, 0, 0);
}

// ---------------------------------------------------------------- qstats (sq + qmean partial)
__global__ __launch_bounds__(256) void qstats(const unsigned short* __restrict__ Qbf,
                                              float* __restrict__ sqout,
                                              float* __restrict__ part) {
    const size_t rbase = ((size_t)(blockIdx.x >> 2) << 10) + ((blockIdx.x & 3) << 8);
    {
        const size_t row = rbase + threadIdx.x;
        const uint4* p = reinterpret_cast<const uint4*>(Qbf + row * 64);
        float s = 0.f;
#pragma unroll
        for (int c = 0; c < 8; c++) {
            uint4 u = p[c];
            unsigned int w4[4] = {u.x, u.y, u.z, u.w};
#pragma unroll
            for (int k = 0; k < 4; k++) {
                float lo = __builtin_bit_cast(float, w4[k] << 16);
                float hi = __builtin_bit_cast(float, w4[k] & 0xffff0000u);
                s += lo * lo + hi * hi;
            }
        }
        sqout[row] = s;
    }
    const int q = threadIdx.x & 63, seg = threadIdx.x >> 6;
    const unsigned short* p = Qbf + (rbase + seg * 64) * 64 + q;
    float m = 0.f;
#pragma unroll 8
    for (int i = 0; i < 64; i++) m += bf2f(p[(size_t)i * 64]);
    __shared__ float red[4][64];
    red[seg][q] = m;
    __syncthreads();
    if (threadIdx.x < 64)
        part[(size_t)blockIdx.x * 64 + threadIdx.x] =
            red[0][threadIdx.x] + red[1][threadIdx.x] + red[2][threadIdx.x] + red[3][threadIdx.x];
}
__global__ __launch_bounds__(256) void qmean_comb(const float* __restrict__ part,
                                                  float* __restrict__ out2) {
    int t = blockIdx.x * 256 + threadIdx.x;  // b*64+q
    int b = t >> 6, q = t & 63;
    float s = 0.f;
#pragma unroll
    for (int d = 0; d < 4; d++)
#pragma unroll
        for (int qt = 0; qt < 4; qt++)
            s += part[(size_t)(((d * 16 + b) << 2) + qt) * 64 + q];
    out2[t] = s * (1.f / 4096.f);
}

// ---------------------------------------------------------------- 128x128 tile GEMM
// AF/BF: 0 = bf16 source via global_load_lds; 1 = fp32 source, reg-staged + cvt in kernel.
// EPI: 0 = PV (fp32 out, /sum of 16 lsum partials); 3 = bf16 out;
//      4 = QH fused (col<256: Q remap -> outv ; col>=256: sigmoid -> out2); B rows from Bv/B2v.
template <int K, int EPI, int AF, int BF>
__global__ __launch_bounds__(256) void tile_gemm(const void* __restrict__ Av,
                                                 const void* __restrict__ Bv,
                                                 const void* __restrict__ B2v,
                                                 const float* __restrict__ bias,
                                                 const float* __restrict__ bias2,
                                                 const float* __restrict__ lsum,
                                                 void* __restrict__ outv,
                                                 unsigned short* __restrict__ out2, int N,
                                                 size_t strideAz, size_t strideBz) {
    __shared__ unsigned short As[2][128 * 32];
    __shared__ unsigned short Bs[2][128 * 32];
    const int bm = blockIdx.x * 128, bn = blockIdx.y * 128, z = blockIdx.z;
    const int tid = threadIdx.x, w = tid >> 6, l = tid & 63;
    const int lrow = l & 15, lk8 = (l >> 4) << 3, r4 = (l >> 4) << 2;
    const int wr = (w >> 1) * 64, wc = (w & 1) * 64;
    const int srow_g = l >> 2, scol_g = (l & 3) * 8;
    const int srow_r = tid >> 1, scol_r = (tid & 1) * 16;
    f32x4 acc[4][4] = {};
    float4 ra[4], rb[4];

    auto issue = [&](int k0, int buf) {
        if constexpr (AF == 0) {
            const unsigned short* Ap = (const unsigned short*)Av + (size_t)z * strideAz;
            gload16(Ap + (size_t)(bm + w * 32 + srow_g) * K + k0 + scol_g,
                    &As[buf][(w * 32) * 32]);
            gload16(Ap + (size_t)(bm + w * 32 + 16 + srow_g) * K + k0 + scol_g,
                    &As[buf][(w * 32 + 16) * 32]);
        } else {
            const float* s = (const float*)Av + (size_t)(bm + srow_r) * K + k0 + scol_r;
            ra[0] = *reinterpret_cast<const float4*>(s);
            ra[1] = *reinterpret_cast<const float4*>(s + 4);
            ra[2] = *reinterpret_cast<const float4*>(s + 8);
            ra[3] = *reinterpret_cast<const float4*>(s + 12);
        }
        if constexpr (BF == 0) {
            const unsigned short* Bp = (const unsigned short*)Bv + (size_t)z * strideBz;
            gload16(Bp + (size_t)(bn + w * 32 + srow_g) * K + k0 + scol_g,
                    &Bs[buf][(w * 32) * 32]);
            gload16(Bp + (size_t)(bn + w * 32 + 16 + srow_g) * K + k0 + scol_g,
                    &Bs[buf][(w * 32 + 16) * 32]);
        } else {
            const int row = bn + srow_r;
            const float* s;
            if constexpr (EPI == 4)
                s = (row < 256 ? (const float*)Bv + (size_t)row * K
                               : (const float*)B2v + (size_t)(row - 256) * K) + k0 + scol_r;
            else
                s = (const float*)Bv + (size_t)row * K + k0 + scol_r;
            rb[0] = *reinterpret_cast<const float4*>(s);
            rb[1] = *reinterpret_cast<const float4*>(s + 4);
            rb[2] = *reinterpret_cast<const float4*>(s + 8);
            rb[3] = *reinterpret_cast<const float4*>(s + 12);
        }
    };
    auto commit = [&](int buf) {
        if constexpr (AF == 1) {
            uint4 w0, w1;
            w0.x = pk2(ra[0].x, ra[0].y); w0.y = pk2(ra[0].z, ra[0].w);
            w0.z = pk2(ra[1].x, ra[1].y); w0.w = pk2(ra[1].z, ra[1].w);
            w1.x = pk2(ra[2].x, ra[2].y); w1.y = pk2(ra[2].z, ra[2].w);
            w1.z = pk2(ra[3].x, ra[3].y); w1.w = pk2(ra[3].z, ra[3].w);
            *reinterpret_cast<uint4*>(&As[buf][srow_r * 32 + scol_r]) = w0;
            *reinterpret_cast<uint4*>(&As[buf][srow_r * 32 + scol_r + 8]) = w1;
        }
        if constexpr (BF == 1) {
            uint4 w0, w1;
            w0.x = pk2(rb[0].x, rb[0].y); w0.y = pk2(rb[0].z, rb[0].w);
            w0.z = pk2(rb[1].x, rb[1].y); w0.w = pk2(rb[1].z, rb[1].w);
            w1.x = pk2(rb[2].x, rb[2].y); w1.y = pk2(rb[2].z, rb[2].w);
            w1.z = pk2(rb[3].x, rb[3].y); w1.w = pk2(rb[3].z, rb[3].w);
            *reinterpret_cast<uint4*>(&Bs[buf][srow_r * 32 + scol_r]) = w0;
            *reinterpret_cast<uint4*>(&Bs[buf][srow_r * 32 + scol_r + 8]) = w1;
        }
    };

    issue(0, 0);
    commit(0);
    __syncthreads();
    int cur = 0;
    const int NKT = K / 32;
    for (int kt = 0; kt < NKT; kt++) {
        if (kt + 1 < NKT) issue((kt + 1) * 32, cur ^ 1);
        bf16x8 af[4], bfr[4];
#pragma unroll
        for (int t = 0; t < 4; t++) {
            af[t] = *reinterpret_cast<const bf16x8*>(&As[cur][(wr + t * 16 + lrow) * 32 + lk8]);
            bfr[t] = *reinterpret_cast<const bf16x8*>(&Bs[cur][(wc + t * 16 + lrow) * 32 + lk8]);
        }
#pragma unroll
        for (int at = 0; at < 4; at++)
#pragma unroll
            for (int bt = 0; bt < 4; bt++) acc[at][bt] = mfma16(af[at], bfr[bt], acc[at][bt]);
        if (kt + 1 < NKT) commit(cur ^ 1);
        __syncthreads();
        cur ^= 1;
    }
#pragma unroll
    for (int at = 0; at < 4; at++) {
        const int i = bm + wr + at * 16 + r4;
        if constexpr (EPI == 0) {
            float* out = (float*)outv;
            float inv[4];
#pragma unroll
            for (int r = 0; r < 4; r++) {
                const size_t row = (size_t)z * 1024 + i + r;
                float s = 0.f;
#pragma unroll
                for (int k = 0; k < 16; k++) s += lsum[(size_t)k * 16384 + row];
                inv[r] = 1.f / s;
            }
#pragma unroll
            for (int bt = 0; bt < 4; bt++) {
                const int y = bn + wc + bt * 16 + lrow;
#pragma unroll
                for (int r = 0; r < 4; r++)
                    out[((size_t)z * 1024 + i + r) * 512 + y] = acc[at][bt][r] * inv[r];
            }
        } else {
            unsigned short* out = (unsigned short*)outv;
#pragma unroll
            for (int bt = 0; bt < 4; bt++) {
                const int col = bn + wc + bt * 16 + lrow;
                const float bv = (EPI == 4) ? (col < 256 ? bias[col] : bias2[col - 256])
                                            : bias[col];
#pragma unroll
                for (int r = 0; r < 4; r++) {
                    const int row = i + r;
                    float v = acc[at][bt][r] + bv;
                    if constexpr (EPI == 3) {
                        out[(size_t)row * N + col] = f2bf_bits(v);
                    } else {  // EPI == 4
                        if (col < 256) {
                            const int d = col >> 6, q = col & 63, lidx = row >> 4, bb = row & 15;
                            out[(((size_t)(d * 16 + bb) << 10) + lidx) * 64 + q] = f2bf_bits(v);
                        } else {
                            float sv = 1.f / (1.f + __expf(-v));
                            out2[(size_t)row * 128 + (col - 256)] = f2bf_bits(sv);
                        }
                    }
                }
            }
        }
    }
}

// ---------------------------------------------------------------- Sin transpose
__global__ __launch_bounds__(256) void transpose_sin(const unsigned short* __restrict__ Sinb,
                                                     unsigned short* __restrict__ SinT) {
    __shared__ unsigned short t[64][65];
    const int l0 = blockIdx.x * 64, y0 = blockIdx.y * 64, b = blockIdx.z;
    const int lane = threadIdx.x & 63, wv = threadIdx.x >> 6;
#pragma unroll
    for (int it = 0; it < 16; it++) {
        int ty = wv * 16 + it;
        t[ty][lane] = Sinb[((size_t)(l0 + ty) * 16 + b) * 512 + y0 + lane];
    }
    __syncthreads();
    const int tx4 = lane & 15, ry0 = lane >> 4;
#pragma unroll
    for (int it = 0; it < 4; it++) {
        int y = wv * 16 + it * 4 + ry0;
        ushort4 v;
        v.x = t[tx4 * 4 + 0][y];
        v.y = t[tx4 * 4 + 1][y];
        v.z = t[tx4 * 4 + 2][y];
        v.w = t[tx4 * 4 + 3][y];
        *reinterpret_cast<ushort4*>(&SinT[((size_t)b * 512 + y0 + y) * 1024 + l0 + tx4 * 4]) = v;
    }
}

// ---------------------------------------------------------------- score (straight-line waves)
// wave = (i-tile of 32, b, j-chunk of 64); 8192 waves. P tile assembled in per-wave LDS
// (stride 88 ushorts: <=4-way banks, 16B-aligned rows), then stored as dense 128B lines.
__global__ __launch_bounds__(256) void score_wave(const unsigned short* __restrict__ Qbf,
                                                  const float* __restrict__ sq,
                                                  unsigned short* __restrict__ P,
                                                  float* __restrict__ lsum) {
    __shared__ unsigned short Pt[4][32 * 88];
    const int w = threadIdx.x >> 6;
    const int gw = blockIdx.x * 4 + w;
    const int l = threadIdx.x & 63;
    const int ti = gw & 31;
    const int b = (gw >> 5) & 15;
    const int jc = gw >> 9;  // 0..15
    const int i0 = ti << 5;
    const int J = jc << 6;
    const int lrow = l & 15, lk8 = (l >> 4) << 3, r4 = (l >> 4) << 2;
    unsigned short* T = &Pt[w][0];

    size_t base[4];
    bf16x8 qi[4][2][2];
    float sqi[4][2];
#pragma unroll
    for (int d = 0; d < 4; d++) {
        base[d] = ((size_t)(d * 16 + b)) << 10;
#pragma unroll
        for (int it = 0; it < 2; it++) {
            const unsigned short* p = Qbf + (base[d] + i0 + it * 16 + lrow) * 64 + lk8;
            qi[d][it][0] = ld8(p);
            qi[d][it][1] = ld8(p + 32);
            sqi[d][it] = sq[base[d] + i0 + it * 16 + lrow];
        }
    }

    const float inv_sx = 0.04419417382415922f;  // 1/sqrt(512)
    float rs[2] = {0.f, 0.f};

    bf16x8 qj[2][4][2];
#pragma unroll
    for (int d = 0; d < 4; d++) {
        const unsigned short* qjp = Qbf + (base[d] + J + lrow) * 64 + lk8;
        qj[0][d][0] = ld8(qjp);
        qj[0][d][1] = ld8(qjp + 32);
    }

#pragma unroll
    for (int t = 0; t < 4; t++) {
        const int j0 = J + t * 16;
        const int cb = t & 1;
        if (t < 3) {
            const int nb = cb ^ 1;
#pragma unroll
            for (int d = 0; d < 4; d++) {
                const unsigned short* qjp = Qbf + (base[d] + j0 + 16 + lrow) * 64 + lk8;
                qj[nb][d][0] = ld8(qjp);
                qj[nb][d][1] = ld8(qjp + 32);
            }
        }
        f32x4 sqj[4];
#pragma unroll
        for (int d = 0; d < 4; d++)
            sqj[d] = *reinterpret_cast<const f32x4*>(&sq[base[d] + j0 + r4]);
        f32x4 sacc[2][4] = {};
#pragma unroll
        for (int d = 0; d < 4; d++) {
            sacc[0][d] = mfma16(qj[cb][d][0], qi[d][0][0], sacc[0][d]);
            sacc[0][d] = mfma16(qj[cb][d][1], qi[d][0][1], sacc[0][d]);
            sacc[1][d] = mfma16(qj[cb][d][0], qi[d][1][0], sacc[1][d]);
            sacc[1][d] = mfma16(qj[cb][d][1], qi[d][1][1], sacc[1][d]);
        }
#pragma unroll
        for (int it = 0; it < 2; it++) {
            float pv[4];
#pragma unroll
            for (int r = 0; r < 4; r++) {
                float s = 0.f;
#pragma unroll
                for (int d = 0; d < 4; d++) {
                    float d2 = fmaxf(sqj[d][r] + sqi[d][it] - 2.f * sacc[it][d][r], 0.f);
                    float dist = __builtin_amdgcn_sqrtf(d2);
                    s += (d & 1) ? -dist : dist;
                }
                pv[r] = __expf(s * inv_sx);
            }
            rs[it] += (pv[0] + pv[1]) + (pv[2] + pv[3]);
            uint2 st;
            st.x = pk2(pv[0], pv[1]);
            st.y = pk2(pv[2], pv[3]);
            *reinterpret_cast<uint2*>(&T[(it * 16 + lrow) * 88 + t * 16 + r4]) = st;
        }
    }
    // dense flush: 4 iters x (8 rows x 128B lines)
#pragma unroll
    for (int k = 0; k < 4; k++) {
        const int ri = k * 8 + (l >> 3), c = l & 7;
        uint4 v = *reinterpret_cast<const uint4*>(&T[ri * 88 + c * 8]);
        *reinterpret_cast<uint4*>(P + ((((size_t)(b << 10)) + i0 + ri) << 10) + J + c * 8) = v;
    }
    rs[0] += __shfl_xor(rs[0], 16);
    rs[0] += __shfl_xor(rs[0], 32);
    rs[1] += __shfl_xor(rs[1], 16);
    rs[1] += __shfl_xor(rs[1], 32);
    if (l < 16) {
        lsum[(size_t)jc * 16384 + ((size_t)b << 10) + i0 + l] = rs[0];
        lsum[(size_t)jc * 16384 + ((size_t)b << 10) + i0 + 16 + l] = rs[1];
    }
}

// ----------------------------------------------------------------------------
extern "C" void kernel_launch(void* const* d_in, const int* in_sizes, int n_in,
                              void* d_out, int out_size, void* d_ws, size_t ws_size,
                              hipStream_t stream) {
    const float* X = (const float*)d_in[0];
    const float* Wq = (const float*)d_in[2];
    const float* bq = (const float*)d_in[3];
    const float* Wh = (const float*)d_in[4];
    const float* bh = (const float*)d_in[5];
    const float* Ws = (const float*)d_in[6];
    const float* bs = (const float*)d_in[7];
    float* out = (float*)d_out;

    char* ws = (char*)d_ws;
    size_t off = 0;
    auto alloc = [&](size_t bytes) {
        void* p = ws + off;
        off = (off + bytes + 255) & ~(size_t)255;
        return p;
    };
    unsigned short* Qbf = (unsigned short*)alloc(4UL * 16 * 1024 * 64 * 2);
    float* sqb = (float*)alloc(4UL * 16 * 1024 * 4);
    unsigned short* Hb = (unsigned short*)alloc(16384UL * 128 * 2);
    unsigned short* Sinb = (unsigned short*)alloc(16384UL * 512 * 2);
    unsigned short* SinT = (unsigned short*)alloc(16UL * 512 * 1024 * 2);
    unsigned short* P = (unsigned short*)alloc(16UL * 1024 * 1024 * 2);  // 32 MB
    float* lsum = (float*)alloc(16UL * 16384 * 4);
    float* qpart = (float*)alloc(256UL * 64 * 4);

    // Qins (remap) + H (sigmoid) fused: C = X * [Wq;Wh]^T, fp32 inputs converted in-kernel
    tile_gemm<512, 4, 1, 1><<<dim3(128, 3, 1), 256, 0, stream>>>(
        X, Wq, Wh, bq, bh, nullptr, Qbf, Hb, 384, 0, 0);
    qstats<<<256, 256, 0, stream>>>(Qbf, sqb, qpart);
    qmean_comb<<<4, 256, 0, stream>>>(qpart, out + 8388608);
    // Sin = H*Ws^T + bs (Ws fp32 reg-staged)
    tile_gemm<128, 3, 0, 1><<<dim3(128, 4, 1), 256, 0, stream>>>(
        Hb, Ws, nullptr, bs, nullptr, nullptr, Sinb, nullptr, 512, 0, 0);
    transpose_sin<<<dim3(16, 8, 16), 256, 0, stream>>>(Sinb, SinT);
    // P = exp(scores), 16 lsum partials
    score_wave<<<2048, 256, 0, stream>>>(Qbf, sqb, P, lsum);
    // Sout = (P @ Sin) / lsum
    tile_gemm<1024, 0, 0, 0><<<dim3(8, 4, 16), 256, 0, stream>>>(
        P, SinT, nullptr, nullptr, nullptr, lsum, out, nullptr, 512, 1024UL * 1024,
        512UL * 1024);
}

// Round 7
// 223.260 us; speedup vs baseline: 1.0280x; 1.0280x over previous
//
#include <hip/hip_runtime.h>

// Problem constants: L=1024, B=16, X=512, Y=512, Q=64, NUM_D=4, H_LOW=128
typedef __bf16 bf16x8 __attribute__((ext_vector_type(8)));
typedef float f32x4 __attribute__((ext_vector_type(4)));

__device__ __forceinline__ unsigned short f2bf_bits(float f) {
    unsigned int u = __builtin_bit_cast(unsigned int, f);
    u += 0x7fffu + ((u >> 16) & 1u);
    return (unsigned short)(u >> 16);
}
__device__ __forceinline__ float bf2f(unsigned short b) {
    return __builtin_bit_cast(float, (unsigned int)b << 16);
}
__device__ __forceinline__ unsigned int pk2(float a, float b) {
    unsigned int r;
    asm("v_cvt_pk_bf16_f32 %0, %1, %2" : "=v"(r) : "v"(a), "v"(b));
    return r;
}
__device__ __forceinline__ bf16x8 ld8(const unsigned short* p) {
    return __builtin_bit_cast(bf16x8, *reinterpret_cast<const uint4*>(p));
}
__device__ __forceinline__ f32x4 mfma16(bf16x8 a, bf16x8 b, f32x4 c) {
    return __builtin_amdgcn_mfma_f32_16x16x32_bf16(a, b, c, 0, 0, 0);
}
__device__ __forceinline__ void gload16(const unsigned short* g, unsigned short* lds) {
    __builtin_amdgcn_global_load_lds(
        (const __attribute__((address_space(1))) unsigned int*)g,
        (__attribute__((address_space(3))) unsigned int*)lds, 16, 0, 0);
}

// ---------------------------------------------------------------- qstats (sq + qmean partial)
__global__ __launch_bounds__(256) void qstats(const unsigned short* __restrict__ Qbf,
                                              float* __restrict__ sqout,
                                              float* __restrict__ part) {
    const size_t rbase = ((size_t)(blockIdx.x >> 2) << 10) + ((blockIdx.x & 3) << 8);
    {
        const size_t row = rbase + threadIdx.x;
        const uint4* p = reinterpret_cast<const uint4*>(Qbf + row * 64);
        float s = 0.f;
#pragma unroll
        for (int c = 0; c < 8; c++) {
            uint4 u = p[c];
            unsigned int w4[4] = {u.x, u.y, u.z, u.w};
#pragma unroll
            for (int k = 0; k < 4; k++) {
                float lo = __builtin_bit_cast(float, w4[k] << 16);
                float hi = __builtin_bit_cast(float, w4[k] & 0xffff0000u);
                s += lo * lo + hi * hi;
            }
        }
        sqout[row] = s;
    }
    const int q = threadIdx.x & 63, seg = threadIdx.x >> 6;
    const unsigned short* p = Qbf + (rbase + seg * 64) * 64 + q;
    float m = 0.f;
#pragma unroll 8
    for (int i = 0; i < 64; i++) m += bf2f(p[(size_t)i * 64]);
    __shared__ float red[4][64];
    red[seg][q] = m;
    __syncthreads();
    if (threadIdx.x < 64)
        part[(size_t)blockIdx.x * 64 + threadIdx.x] =
            red[0][threadIdx.x] + red[1][threadIdx.x] + red[2][threadIdx.x] + red[3][threadIdx.x];
}
__global__ __launch_bounds__(256) void qmean_comb(const float* __restrict__ part,
                                                  float* __restrict__ out2) {
    int t = blockIdx.x * 256 + threadIdx.x;  // b*64+q
    int b = t >> 6, q = t & 63;
    float s = 0.f;
#pragma unroll
    for (int d = 0; d < 4; d++)
#pragma unroll
        for (int qt = 0; qt < 4; qt++)
            s += part[(size_t)(((d * 16 + b) << 2) + qt) * 64 + q];
    out2[t] = s * (1.f / 4096.f);
}

// ---------------------------------------------------------------- 128x128 tile GEMM
// AF/BF: 0 = bf16 via global_load_lds; 1 = fp32 source reg-staged + cvt in kernel.
// EPI: 0 = PV (fp32 out, /sum of 16 lsum partials); 3 = bf16 out; 4 = QH fused.
// SWZ: 1 = linear 512-block grid with XCD-pinned z (z = 2*(bid&7)+(u&1)).
template <int K, int EPI, int AF, int BF, int SWZ>
__global__ __launch_bounds__(256) void tile_gemm(const void* __restrict__ Av,
                                                 const void* __restrict__ Bv,
                                                 const void* __restrict__ B2v,
                                                 const float* __restrict__ bias,
                                                 const float* __restrict__ bias2,
                                                 const float* __restrict__ lsum,
                                                 void* __restrict__ outv,
                                                 unsigned short* __restrict__ out2, int N,
                                                 size_t strideAz, size_t strideBz) {
    __shared__ unsigned short As[2][128 * 32];
    __shared__ unsigned short Bs[2][128 * 32];
    int bm, bn, z;
    if constexpr (SWZ) {
        const int bid = blockIdx.x;          // 512 linear
        const int u = bid >> 3;              // 0..63
        z = ((bid & 7) << 1) | (u & 1);      // XCD (bid&7) owns z in {2k,2k+1}
        const int v = u >> 1;                // 0..31
        bm = (v & 7) * 128;
        bn = (v >> 3) * 128;
    } else {
        bm = blockIdx.x * 128;
        bn = blockIdx.y * 128;
        z = blockIdx.z;
    }
    const int tid = threadIdx.x, w = tid >> 6, l = tid & 63;
    const int lrow = l & 15, lk8 = (l >> 4) << 3, r4 = (l >> 4) << 2;
    const int wr = (w >> 1) * 64, wc = (w & 1) * 64;
    const int srow_g = l >> 2, scol_g = (l & 3) * 8;
    const int srow_r = tid >> 1, scol_r = (tid & 1) * 16;
    f32x4 acc[4][4] = {};
    float4 ra[4], rb[4];

    auto issue = [&](int k0, int buf) {
        if constexpr (AF == 0) {
            const unsigned short* Ap = (const unsigned short*)Av + (size_t)z * strideAz;
            gload16(Ap + (size_t)(bm + w * 32 + srow_g) * K + k0 + scol_g,
                    &As[buf][(w * 32) * 32]);
            gload16(Ap + (size_t)(bm + w * 32 + 16 + srow_g) * K + k0 + scol_g,
                    &As[buf][(w * 32 + 16) * 32]);
        } else {
            const float* s = (const float*)Av + (size_t)(bm + srow_r) * K + k0 + scol_r;
            ra[0] = *reinterpret_cast<const float4*>(s);
            ra[1] = *reinterpret_cast<const float4*>(s + 4);
            ra[2] = *reinterpret_cast<const float4*>(s + 8);
            ra[3] = *reinterpret_cast<const float4*>(s + 12);
        }
        if constexpr (BF == 0) {
            const unsigned short* Bp = (const unsigned short*)Bv + (size_t)z * strideBz;
            gload16(Bp + (size_t)(bn + w * 32 + srow_g) * K + k0 + scol_g,
                    &Bs[buf][(w * 32) * 32]);
            gload16(Bp + (size_t)(bn + w * 32 + 16 + srow_g) * K + k0 + scol_g,
                    &Bs[buf][(w * 32 + 16) * 32]);
        } else {
            const int row = bn + srow_r;
            const float* s;
            if constexpr (EPI == 4)
                s = (row < 256 ? (const float*)Bv + (size_t)row * K
                               : (const float*)B2v + (size_t)(row - 256) * K) + k0 + scol_r;
            else
                s = (const float*)Bv + (size_t)row * K + k0 + scol_r;
            rb[0] = *reinterpret_cast<const float4*>(s);
            rb[1] = *reinterpret_cast<const float4*>(s + 4);
            rb[2] = *reinterpret_cast<const float4*>(s + 8);
            rb[3] = *reinterpret_cast<const float4*>(s + 12);
        }
    };
    auto commit = [&](int buf) {
        if constexpr (AF == 1) {
            uint4 w0, w1;
            w0.x = pk2(ra[0].x, ra[0].y); w0.y = pk2(ra[0].z, ra[0].w);
            w0.z = pk2(ra[1].x, ra[1].y); w0.w = pk2(ra[1].z, ra[1].w);
            w1.x = pk2(ra[2].x, ra[2].y); w1.y = pk2(ra[2].z, ra[2].w);
            w1.z = pk2(ra[3].x, ra[3].y); w1.w = pk2(ra[3].z, ra[3].w);
            *reinterpret_cast<uint4*>(&As[buf][srow_r * 32 + scol_r]) = w0;
            *reinterpret_cast<uint4*>(&As[buf][srow_r * 32 + scol_r + 8]) = w1;
        }
        if constexpr (BF == 1) {
            uint4 w0, w1;
            w0.x = pk2(rb[0].x, rb[0].y); w0.y = pk2(rb[0].z, rb[0].w);
            w0.z = pk2(rb[1].x, rb[1].y); w0.w = pk2(rb[1].z, rb[1].w);
            w1.x = pk2(rb[2].x, rb[2].y); w1.y = pk2(rb[2].z, rb[2].w);
            w1.z = pk2(rb[3].x, rb[3].y); w1.w = pk2(rb[3].z, rb[3].w);
            *reinterpret_cast<uint4*>(&Bs[buf][srow_r * 32 + scol_r]) = w0;
            *reinterpret_cast<uint4*>(&Bs[buf][srow_r * 32 + scol_r + 8]) = w1;
        }
    };

    issue(0, 0);
    commit(0);
    __syncthreads();
    int cur = 0;
    const int NKT = K / 32;
    for (int kt = 0; kt < NKT; kt++) {
        if (kt + 1 < NKT) issue((kt + 1) * 32, cur ^ 1);
        bf16x8 af[4], bfr[4];
#pragma unroll
        for (int t = 0; t < 4; t++) {
            af[t] = *reinterpret_cast<const bf16x8*>(&As[cur][(wr + t * 16 + lrow) * 32 + lk8]);
            bfr[t] = *reinterpret_cast<const bf16x8*>(&Bs[cur][(wc + t * 16 + lrow) * 32 + lk8]);
        }
#pragma unroll
        for (int at = 0; at < 4; at++)
#pragma unroll
            for (int bt = 0; bt < 4; bt++) acc[at][bt] = mfma16(af[at], bfr[bt], acc[at][bt]);
        if (kt + 1 < NKT) commit(cur ^ 1);
        __syncthreads();
        cur ^= 1;
    }
#pragma unroll
    for (int at = 0; at < 4; at++) {
        const int i = bm + wr + at * 16 + r4;
        if constexpr (EPI == 0) {
            float* out = (float*)outv;
            float inv[4];
#pragma unroll
            for (int r = 0; r < 4; r++) {
                const size_t row = (size_t)z * 1024 + i + r;
                float s = 0.f;
#pragma unroll
                for (int k = 0; k < 16; k++) s += lsum[(size_t)k * 16384 + row];
                inv[r] = 1.f / s;
            }
#pragma unroll
            for (int bt = 0; bt < 4; bt++) {
                const int y = bn + wc + bt * 16 + lrow;
#pragma unroll
                for (int r = 0; r < 4; r++)
                    out[((size_t)z * 1024 + i + r) * 512 + y] = acc[at][bt][r] * inv[r];
            }
        } else {
            unsigned short* out = (unsigned short*)outv;
#pragma unroll
            for (int bt = 0; bt < 4; bt++) {
                const int col = bn + wc + bt * 16 + lrow;
                const float bv = (EPI == 4) ? (col < 256 ? bias[col] : bias2[col - 256])
                                            : bias[col];
#pragma unroll
                for (int r = 0; r < 4; r++) {
                    const int row = i + r;
                    float v = acc[at][bt][r] + bv;
                    if constexpr (EPI == 3) {
                        out[(size_t)row * N + col] = f2bf_bits(v);
                    } else {  // EPI == 4
                        if (col < 256) {
                            const int d = col >> 6, q = col & 63, lidx = row >> 4, bb = row & 15;
                            out[(((size_t)(d * 16 + bb) << 10) + lidx) * 64 + q] = f2bf_bits(v);
                        } else {
                            float sv = 1.f / (1.f + __expf(-v));
                            out2[(size_t)row * 128 + (col - 256)] = f2bf_bits(sv);
                        }
                    }
                }
            }
        }
    }
}

// ---------------------------------------------------------------- Sin transpose
__global__ __launch_bounds__(256) void transpose_sin(const unsigned short* __restrict__ Sinb,
                                                     unsigned short* __restrict__ SinT) {
    __shared__ unsigned short t[64][65];
    const int l0 = blockIdx.x * 64, y0 = blockIdx.y * 64, b = blockIdx.z;
    const int lane = threadIdx.x & 63, wv = threadIdx.x >> 6;
#pragma unroll
    for (int it = 0; it < 16; it++) {
        int ty = wv * 16 + it;
        t[ty][lane] = Sinb[((size_t)(l0 + ty) * 16 + b) * 512 + y0 + lane];
    }
    __syncthreads();
    const int tx4 = lane & 15, ry0 = lane >> 4;
#pragma unroll
    for (int it = 0; it < 4; it++) {
        int y = wv * 16 + it * 4 + ry0;
        ushort4 v;
        v.x = t[tx4 * 4 + 0][y];
        v.y = t[tx4 * 4 + 1][y];
        v.z = t[tx4 * 4 + 2][y];
        v.w = t[tx4 * 4 + 3][y];
        *reinterpret_cast<ushort4*>(&SinT[((size_t)b * 512 + y0 + y) * 1024 + l0 + tx4 * 4]) = v;
    }
}

// ---------------------------------------------------------------- score (XCD-pinned b)
// XCD k (= bid&7) exclusively handles b in {2k,2k+1}: per-XCD Qbf working set = 1 MB ⊂ L2.
// Block's 4 waves share (b, i-tile), split j. Per-wave LDS P-tile -> dense 128B-line stores.
__global__ __launch_bounds__(256) void score_wave(const unsigned short* __restrict__ Qbf,
                                                  const float* __restrict__ sq,
                                                  unsigned short* __restrict__ P,
                                                  float* __restrict__ lsum) {
    __shared__ unsigned short Pt[4][32 * 88];
    const int w = threadIdx.x >> 6;
    const int l = threadIdx.x & 63;
    const int bid = blockIdx.x;            // 0..2047
    const int u = bid >> 3;                // 0..255
    const int b = ((bid & 7) << 1) | (u & 1);
    const int u2 = u >> 1;                 // 0..127
    const int ti = u2 & 31;
    const int jgrp = u2 >> 5;              // 0..3
    const int jc = (jgrp << 2) | w;        // 0..15
    const int i0 = ti << 5;
    const int J = jc << 6;
    const int lrow = l & 15, lk8 = (l >> 4) << 3, r4 = (l >> 4) << 2;
    unsigned short* T = &Pt[w][0];

    size_t base[4];
    bf16x8 qi[4][2][2];
    float sqi[4][2];
#pragma unroll
    for (int d = 0; d < 4; d++) {
        base[d] = ((size_t)(d * 16 + b)) << 10;
#pragma unroll
        for (int it = 0; it < 2; it++) {
            const unsigned short* p = Qbf + (base[d] + i0 + it * 16 + lrow) * 64 + lk8;
            qi[d][it][0] = ld8(p);
            qi[d][it][1] = ld8(p + 32);
            sqi[d][it] = sq[base[d] + i0 + it * 16 + lrow];
        }
    }

    const float inv_sx = 0.04419417382415922f;  // 1/sqrt(512)
    float rs[2] = {0.f, 0.f};

    bf16x8 qj[2][4][2];
#pragma unroll
    for (int d = 0; d < 4; d++) {
        const unsigned short* qjp = Qbf + (base[d] + J + lrow) * 64 + lk8;
        qj[0][d][0] = ld8(qjp);
        qj[0][d][1] = ld8(qjp + 32);
    }

#pragma unroll
    for (int t = 0; t < 4; t++) {
        const int j0 = J + t * 16;
        const int cb = t & 1;
        if (t < 3) {
            const int nb = cb ^ 1;
#pragma unroll
            for (int d = 0; d < 4; d++) {
                const unsigned short* qjp = Qbf + (base[d] + j0 + 16 + lrow) * 64 + lk8;
                qj[nb][d][0] = ld8(qjp);
                qj[nb][d][1] = ld8(qjp + 32);
            }
        }
        f32x4 sqj[4];
#pragma unroll
        for (int d = 0; d < 4; d++)
            sqj[d] = *reinterpret_cast<const f32x4*>(&sq[base[d] + j0 + r4]);
        f32x4 sacc[2][4] = {};
#pragma unroll
        for (int d = 0; d < 4; d++) {
            sacc[0][d] = mfma16(qj[cb][d][0], qi[d][0][0], sacc[0][d]);
            sacc[0][d] = mfma16(qj[cb][d][1], qi[d][0][1], sacc[0][d]);
            sacc[1][d] = mfma16(qj[cb][d][0], qi[d][1][0], sacc[1][d]);
            sacc[1][d] = mfma16(qj[cb][d][1], qi[d][1][1], sacc[1][d]);
        }
#pragma unroll
        for (int it = 0; it < 2; it++) {
            float pv[4];
#pragma unroll
            for (int r = 0; r < 4; r++) {
                float s = 0.f;
#pragma unroll
                for (int d = 0; d < 4; d++) {
                    float d2 = fmaxf(sqj[d][r] + sqi[d][it] - 2.f * sacc[it][d][r], 0.f);
                    float dist = __builtin_amdgcn_sqrtf(d2);
                    s += (d & 1) ? -dist : dist;
                }
                pv[r] = __expf(s * inv_sx);
            }
            rs[it] += (pv[0] + pv[1]) + (pv[2] + pv[3]);
            uint2 st;
            st.x = pk2(pv[0], pv[1]);
            st.y = pk2(pv[2], pv[3]);
            *reinterpret_cast<uint2*>(&T[(it * 16 + lrow) * 88 + t * 16 + r4]) = st;
        }
    }
    // dense flush: 4 iters x (8 rows x 128B lines)
#pragma unroll
    for (int k = 0; k < 4; k++) {
        const int ri = k * 8 + (l >> 3), c = l & 7;
        uint4 v = *reinterpret_cast<const uint4*>(&T[ri * 88 + c * 8]);
        *reinterpret_cast<uint4*>(P + ((((size_t)(b << 10)) + i0 + ri) << 10) + J + c * 8) = v;
    }
    rs[0] += __shfl_xor(rs[0], 16);
    rs[0] += __shfl_xor(rs[0], 32);
    rs[1] += __shfl_xor(rs[1], 16);
    rs[1] += __shfl_xor(rs[1], 32);
    if (l < 16) {
        lsum[(size_t)jc * 16384 + ((size_t)b << 10) + i0 + l] = rs[0];
        lsum[(size_t)jc * 16384 + ((size_t)b << 10) + i0 + 16 + l] = rs[1];
    }
}

// ----------------------------------------------------------------------------
extern "C" void kernel_launch(void* const* d_in, const int* in_sizes, int n_in,
                              void* d_out, int out_size, void* d_ws, size_t ws_size,
                              hipStream_t stream) {
    const float* X = (const float*)d_in[0];
    const float* Wq = (const float*)d_in[2];
    const float* bq = (const float*)d_in[3];
    const float* Wh = (const float*)d_in[4];
    const float* bh = (const float*)d_in[5];
    const float* Ws = (const float*)d_in[6];
    const float* bs = (const float*)d_in[7];
    float* out = (float*)d_out;

    char* ws = (char*)d_ws;
    size_t off = 0;
    auto alloc = [&](size_t bytes) {
        void* p = ws + off;
        off = (off + bytes + 255) & ~(size_t)255;
        return p;
    };
    unsigned short* Qbf = (unsigned short*)alloc(4UL * 16 * 1024 * 64 * 2);
    float* sqb = (float*)alloc(4UL * 16 * 1024 * 4);
    unsigned short* Hb = (unsigned short*)alloc(16384UL * 128 * 2);
    unsigned short* Sinb = (unsigned short*)alloc(16384UL * 512 * 2);
    unsigned short* SinT = (unsigned short*)alloc(16UL * 512 * 1024 * 2);
    unsigned short* P = (unsigned short*)alloc(16UL * 1024 * 1024 * 2);  // 32 MB
    float* lsum = (float*)alloc(16UL * 16384 * 4);
    float* qpart = (float*)alloc(256UL * 64 * 4);

    // Qins (remap) + H (sigmoid) fused: C = X * [Wq;Wh]^T, fp32 inputs converted in-kernel
    tile_gemm<512, 4, 1, 1, 0><<<dim3(128, 3, 1), 256, 0, stream>>>(
        X, Wq, Wh, bq, bh, nullptr, Qbf, Hb, 384, 0, 0);
    qstats<<<256, 256, 0, stream>>>(Qbf, sqb, qpart);
    qmean_comb<<<4, 256, 0, stream>>>(qpart, out + 8388608);
    // Sin = H*Ws^T + bs (Ws fp32 reg-staged)
    tile_gemm<128, 3, 0, 1, 0><<<dim3(128, 4, 1), 256, 0, stream>>>(
        Hb, Ws, nullptr, bs, nullptr, nullptr, Sinb, nullptr, 512, 0, 0);
    transpose_sin<<<dim3(16, 8, 16), 256, 0, stream>>>(Sinb, SinT);
    // P = exp(scores), 16 lsum partials (XCD-pinned b)
    score_wave<<<2048, 256, 0, stream>>>(Qbf, sqb, P, lsum);
    // Sout = (P @ Sin) / lsum  (XCD-pinned z)
    tile_gemm<1024, 0, 0, 0, 1><<<512, 256, 0, stream>>>(
        P, SinT, nullptr, nullptr, nullptr, lsum, out, nullptr, 512, 1024UL * 1024,
        512UL * 1024);
}